// Round 8
// baseline (194.506 us; speedup 1.0000x reference)
//
#include <hip/hip_runtime.h>
#include <math.h>

// ---------------------------------------------------------------------------
// e3nn tensor product: 64x0e+64x1o+64x2e  (x)  1x0e+1x1o+1x2e -> 18 CG paths,
// output sorted-concat to 72 floats per (batch, channel u), 4608 per batch row.
//
// R8: FUSED + DIAGNOSTIC.
//  - m_kernel deleted: each path recomputes its (lane-uniform) M values from
//    cg (global, wave-uniform addr -> scalar loads) and x2 (9 uniform loads),
//    with FMA ordering identical to the proven m_kernel+tp_bounce chain.
//    Removes one launch + the 35 MB M round-trip.
//  - R7's proven mechanics kept verbatim: lane=u x1 in registers, odd-stride
//    LDS bounce, wave_barrier+asm-fence pairs (validated correct in R7),
//    dense dwordx4 stores, no s_barrier anywhere.
//  - DIAGNOSTIC: path/store phase runs rep(=3, runtime arg) times so tp_fused
//    exceeds the harness 1.2GB fills (~180us) and surfaces in the rocprof
//    top-5 with the new structure's counters. R9 interprets, sets rep=1.
// ---------------------------------------------------------------------------

namespace {
constexpr int NP = 18;
constexpr int P_CH1[NP] = {0,0,0,1,1,1,1,1,1,1,2,2,2,2,2,2,2,2}; // l1
constexpr int P_CH2[NP] = {0,1,2,0,1,1,1,2,2,2,0,1,1,1,2,2,2,2}; // l2
constexpr int P_LO [NP] = {0,1,2,1,0,1,2,1,2,3,2,1,2,3,0,1,2,3};
// output column offset of each path's chunk (64*(2lo+1) wide), sorted order
constexpr int P_OUT[NP] = {0,192,1344,384,64,960,1664,576,2624,3264,
                           1984,768,2944,3712,128,1152,2304,4160};
// CG table offsets (floats), sizes (2l1+1)(2l2+1)(2lo+1)
constexpr int C_OFF[NP] = {0,1,10,35,44,53,80,125,170,245,350,375,420,495,600,625,700,825};
// input2 column offset per chunk
constexpr int X2_OFF[3] = {0,1,4};
}

// ------------------------- CG table construction (fp64) --------------------

struct cdbl { double re, im; };
__device__ inline cdbl cmul(cdbl a, cdbl b){
  return { a.re*b.re - a.im*b.im, a.re*b.im + a.im*b.re };
}

__device__ inline double dfact(int n){
  const double F[9] = {1.,1.,2.,6.,24.,120.,720.,5040.,40320.};
  return F[n];
}

__device__ double su2cg(int j1,int m1,int j2,int m2,int j3,int m3){
  if (m1 + m2 != m3) return 0.0;
  int vmin = max(max(-j1 + j2 + m3, -j1 + m1), 0);
  int vmax = min(min(j2 + j3 + m1, j3 - j1 + j2), j3 + m3);
  if (vmax < vmin) return 0.0;
  double C = sqrt((2.0*j3 + 1.0)
      * dfact(j3 + j1 - j2) * dfact(j3 - j1 + j2) * dfact(j1 + j2 - j3)
      * dfact(j3 + m3) * dfact(j3 - m3)
      / (dfact(j1 + j2 + j3 + 1) * dfact(j1 - m1) * dfact(j1 + m1)
         * dfact(j2 - m2) * dfact(j2 + m2)));
  double S = 0.0;
  for (int v = vmin; v <= vmax; ++v){
    double t = dfact(j2 + j3 + m1 - v) * dfact(j1 - m1 + v)
        / (dfact(v) * dfact(j3 - j1 + j2 - v) * dfact(j3 + m3 - v)
           * dfact(v + j1 - j2 - m3));
    S += (((v + j2 + m2) & 1) ? -t : t);
  }
  return C * S;
}

// change_basis_real_to_complex(l)[row][col], including the (-i)^l prefactor
__device__ cdbl Qval(int l, int row, int col){
  const double s2 = 0.70710678118654752440;
  int m = row - l;
  cdbl v = {0.0, 0.0};
  if (m < 0){
    if (col == l - m)       v = { s2, 0.0 };
    else if (col == l + m)  v = { 0.0, -s2 };
  } else if (m == 0){
    if (col == l)           v = { 1.0, 0.0 };
  } else {
    double sg = (m & 1) ? -1.0 : 1.0;
    if (col == l + m)       v = { sg*s2, 0.0 };
    else if (col == l - m)  v = { 0.0, sg*s2 };
  }
  cdbl ph;
  switch (l & 3){            // (-i)^l
    case 0: ph = { 1.0, 0.0 }; break;
    case 1: ph = { 0.0,-1.0 }; break;
    case 2: ph = {-1.0, 0.0 }; break;
    default: ph = { 0.0, 1.0 }; break;
  }
  return cmul(ph, v);
}

// one block per path; thread e computes real CG entry [a1][a2][a3]
__global__ __launch_bounds__(256) void cg_init(float* __restrict__ cg){
  int p = blockIdx.x;
  int l1 = P_CH1[p], l2 = P_CH2[p], l3 = P_LO[p];
  int n1 = 2*l1+1, n2 = 2*l2+1, n3 = 2*l3+1;
  int sz = n1*n2*n3;
  int e = threadIdx.x;
  if (e >= sz) return;
  int a1 = e / (n2*n3);
  int r  = e - a1*(n2*n3);
  int a2 = r / n3;
  int a3 = r - a2*n3;
  double acc = 0.0;
  for (int i = 0; i < n1; ++i){
    for (int k = 0; k < n2; ++k){
      int m1 = i - l1, m2 = k - l2, m3 = m1 + m2;
      if (m3 < -l3 || m3 > l3) continue;
      double a = su2cg(l1, m1, l2, m2, l3, m3);
      if (a == 0.0) continue;
      cdbl q1 = Qval(l1, i, a1);
      cdbl q2 = Qval(l2, k, a2);
      cdbl q3 = Qval(l3, l3 + m3, a3);
      q3.im = -q3.im;                      // conj (Q3.conj().T)
      cdbl t = cmul(cmul(q1, q2), q3);
      acc += t.re * a;                     // imag cancels (asserted in ref)
    }
  }
  cg[C_OFF[p] + e] = (float)acc;
}

// ------------------------- fused main kernel -------------------------------

template<int P>
__device__ __forceinline__ void do_path(const float xall[9], const float x2v[9],
                                        const float* __restrict__ cg,  // uniform
                                        float* __restrict__ bbf,       // wave bounce
                                        float4* __restrict__ ob4, int t){
  constexpr int l1 = P_CH1[P], l2 = P_CH2[P];
  constexpr int n1 = 2*l1+1, n2 = 2*l2+1, no = 2*P_LO[P]+1;
  constexpr int XO  = (l1 == 0) ? 0 : (l1 == 1 ? 1 : 4);
  constexpr int X2O = X2_OFF[l2];
  constexpr int B4  = P_OUT[P] >> 2;   // float4 base of this chunk
  constexpr int NF4 = 16*no;           // float4 count in this chunk

  // lane-uniform M values, recomputed (same FMA order as the proven m_kernel)
  float m[no][n1];
  #pragma unroll
  for (int io = 0; io < no; ++io)
    #pragma unroll
    for (int i1 = 0; i1 < n1; ++i1){
      float s = 0.f;
      #pragma unroll
      for (int j = 0; j < n2; ++j)
        s = fmaf(cg[C_OFF[P] + (i1*n2 + j)*no + io], x2v[X2O + j], s);
      m[io][i1] = s;
    }

  // lane u's no outputs (same order as proven tp_bounce)
  #pragma unroll
  for (int io = 0; io < no; ++io){
    float acc = 0.f;
    #pragma unroll
    for (int i1 = 0; i1 < n1; ++i1)
      acc = fmaf(xall[XO + i1], m[io][i1], acc);
    bbf[t*no + io] = acc;              // odd stride -> <=2 lanes/bank, free
  }
  // compiler fence for cross-lane LDS (HW DS in-order per wave) — proven R7
  __builtin_amdgcn_wave_barrier();
  asm volatile("" ::: "memory");

  const float4* bb4 = (const float4*)bbf;
  if constexpr (NF4 >= 64){
    ob4[B4 + t] = bb4[t];
    if constexpr (NF4 > 64){
      if (t < NF4 - 64) ob4[B4 + 64 + t] = bb4[64 + t];
    }
  } else {
    if (t < NF4) ob4[B4 + t] = bb4[t];
  }

  __builtin_amdgcn_wave_barrier();     // WAR: next path's writes stay after reads
  asm volatile("" ::: "memory");
}

// 256 threads = 4 waves = 4 rows, no __syncthreads (waves independent).
// DIAGNOSTIC: path phase repeated `rep` times (runtime arg, not DCE-able);
// inputs in regs / LDS overwritten identically -> passes idempotent.
__global__ __launch_bounds__(256) void tp_fused(const float* __restrict__ x1,
    const float* __restrict__ x2, const float* __restrict__ cg,
    float* __restrict__ out, int batch, int rep){
  __shared__ __align__(16) float bnc[4][456];
  const int t = threadIdx.x & 63;
  int b = blockIdx.x * 4 + (threadIdx.x >> 6);
  if (b >= batch) b = batch - 1;            // benign duplicate
  b = __builtin_amdgcn_readfirstlane(b);
  float* bbf = bnc[threadIdx.x >> 6];

  // x1 channel values straight to registers
  const float* xr = x1 + (size_t)b * 576;
  float xall[9];
  xall[0] = xr[t];
  xall[1] = xr[64 + 3*t]; xall[2] = xr[65 + 3*t]; xall[3] = xr[66 + 3*t];
  #pragma unroll
  for (int i = 0; i < 5; ++i) xall[4+i] = xr[256 + 5*t + i];

  // x2 row: wave-uniform -> scalar loads
  const float* x2b = x2 + (size_t)b * 9;
  float x2v[9];
  #pragma unroll
  for (int j = 0; j < 9; ++j) x2v[j] = x2b[j];

  float4* ob4 = (float4*)(out + (size_t)b * 4608);

  #pragma unroll 1
  for (int r = 0; r < rep; ++r){
    do_path< 0>(xall, x2v, cg, bbf, ob4, t);
    do_path< 1>(xall, x2v, cg, bbf, ob4, t);
    do_path< 2>(xall, x2v, cg, bbf, ob4, t);
    do_path< 3>(xall, x2v, cg, bbf, ob4, t);
    do_path< 4>(xall, x2v, cg, bbf, ob4, t);
    do_path< 5>(xall, x2v, cg, bbf, ob4, t);
    do_path< 6>(xall, x2v, cg, bbf, ob4, t);
    do_path< 7>(xall, x2v, cg, bbf, ob4, t);
    do_path< 8>(xall, x2v, cg, bbf, ob4, t);
    do_path< 9>(xall, x2v, cg, bbf, ob4, t);
    do_path<10>(xall, x2v, cg, bbf, ob4, t);
    do_path<11>(xall, x2v, cg, bbf, ob4, t);
    do_path<12>(xall, x2v, cg, bbf, ob4, t);
    do_path<13>(xall, x2v, cg, bbf, ob4, t);
    do_path<14>(xall, x2v, cg, bbf, ob4, t);
    do_path<15>(xall, x2v, cg, bbf, ob4, t);
    do_path<16>(xall, x2v, cg, bbf, ob4, t);
    do_path<17>(xall, x2v, cg, bbf, ob4, t);
  }
}

extern "C" void kernel_launch(void* const* d_in, const int* in_sizes, int n_in,
                              void* d_out, int out_size, void* d_ws, size_t ws_size,
                              hipStream_t stream){
  const float* x1 = (const float*)d_in[0];
  const float* x2 = (const float*)d_in[1];
  float* out = (float*)d_out;
  const int batch = in_sizes[0] / 576;

  float* cg = (float*)d_ws;                       // 1000 floats (ws >= 4 KiB)

  cg_init<<<NP, 256, 0, stream>>>(cg);
  tp_fused<<<(batch + 3)/4, 256, 0, stream>>>(x1, x2, cg, out, batch, /*rep=*/3);
}

// Round 9
// 96.823 us; speedup vs baseline: 2.0089x; 2.0089x over previous
//
#include <hip/hip_runtime.h>
#include <math.h>

// ---------------------------------------------------------------------------
// e3nn tensor product: 64x0e+64x1o+64x2e  (x)  1x0e+1x1o+1x2e -> 18 CG paths,
// output sorted-concat to 72 floats per (batch, channel u), 4608 per batch row.
//
// R9: R8's fused structure with the diagnostic repetition removed (rep=1).
//  R8 counters (rep=3): WRITE=3x294MB (passes write through to HBM), 4.65TB/s,
//  VALUBusy 55%, conflicts 0 -> per-pass ~65us, store-stream-dominated with
//  a quantified VALU secondary term (M recompute). rep=1 ~= 67us + cg_init.
//  - single fused kernel: per-path M recomputed from cg (wave-uniform scalar
//    loads) and x2 (uniform), same FMA order as the proven m_kernel chain.
//  - lane=u x1 in registers; odd-stride LDS bounce; wave_barrier+asm-fence
//    pairs (proven R7/R8); dense dwordx4 stores; no s_barrier.
// ---------------------------------------------------------------------------

namespace {
constexpr int NP = 18;
constexpr int P_CH1[NP] = {0,0,0,1,1,1,1,1,1,1,2,2,2,2,2,2,2,2}; // l1
constexpr int P_CH2[NP] = {0,1,2,0,1,1,1,2,2,2,0,1,1,1,2,2,2,2}; // l2
constexpr int P_LO [NP] = {0,1,2,1,0,1,2,1,2,3,2,1,2,3,0,1,2,3};
// output column offset of each path's chunk (64*(2lo+1) wide), sorted order
constexpr int P_OUT[NP] = {0,192,1344,384,64,960,1664,576,2624,3264,
                           1984,768,2944,3712,128,1152,2304,4160};
// CG table offsets (floats), sizes (2l1+1)(2l2+1)(2lo+1)
constexpr int C_OFF[NP] = {0,1,10,35,44,53,80,125,170,245,350,375,420,495,600,625,700,825};
// input2 column offset per chunk
constexpr int X2_OFF[3] = {0,1,4};
}

// ------------------------- CG table construction (fp64) --------------------

struct cdbl { double re, im; };
__device__ inline cdbl cmul(cdbl a, cdbl b){
  return { a.re*b.re - a.im*b.im, a.re*b.im + a.im*b.re };
}

__device__ inline double dfact(int n){
  const double F[9] = {1.,1.,2.,6.,24.,120.,720.,5040.,40320.};
  return F[n];
}

__device__ double su2cg(int j1,int m1,int j2,int m2,int j3,int m3){
  if (m1 + m2 != m3) return 0.0;
  int vmin = max(max(-j1 + j2 + m3, -j1 + m1), 0);
  int vmax = min(min(j2 + j3 + m1, j3 - j1 + j2), j3 + m3);
  if (vmax < vmin) return 0.0;
  double C = sqrt((2.0*j3 + 1.0)
      * dfact(j3 + j1 - j2) * dfact(j3 - j1 + j2) * dfact(j1 + j2 - j3)
      * dfact(j3 + m3) * dfact(j3 - m3)
      / (dfact(j1 + j2 + j3 + 1) * dfact(j1 - m1) * dfact(j1 + m1)
         * dfact(j2 - m2) * dfact(j2 + m2)));
  double S = 0.0;
  for (int v = vmin; v <= vmax; ++v){
    double t = dfact(j2 + j3 + m1 - v) * dfact(j1 - m1 + v)
        / (dfact(v) * dfact(j3 - j1 + j2 - v) * dfact(j3 + m3 - v)
           * dfact(v + j1 - j2 - m3));
    S += (((v + j2 + m2) & 1) ? -t : t);
  }
  return C * S;
}

// change_basis_real_to_complex(l)[row][col], including the (-i)^l prefactor
__device__ cdbl Qval(int l, int row, int col){
  const double s2 = 0.70710678118654752440;
  int m = row - l;
  cdbl v = {0.0, 0.0};
  if (m < 0){
    if (col == l - m)       v = { s2, 0.0 };
    else if (col == l + m)  v = { 0.0, -s2 };
  } else if (m == 0){
    if (col == l)           v = { 1.0, 0.0 };
  } else {
    double sg = (m & 1) ? -1.0 : 1.0;
    if (col == l + m)       v = { sg*s2, 0.0 };
    else if (col == l - m)  v = { 0.0, sg*s2 };
  }
  cdbl ph;
  switch (l & 3){            // (-i)^l
    case 0: ph = { 1.0, 0.0 }; break;
    case 1: ph = { 0.0,-1.0 }; break;
    case 2: ph = {-1.0, 0.0 }; break;
    default: ph = { 0.0, 1.0 }; break;
  }
  return cmul(ph, v);
}

// one block per path; thread e computes real CG entry [a1][a2][a3]
__global__ __launch_bounds__(256) void cg_init(float* __restrict__ cg){
  int p = blockIdx.x;
  int l1 = P_CH1[p], l2 = P_CH2[p], l3 = P_LO[p];
  int n1 = 2*l1+1, n2 = 2*l2+1, n3 = 2*l3+1;
  int sz = n1*n2*n3;
  int e = threadIdx.x;
  if (e >= sz) return;
  int a1 = e / (n2*n3);
  int r  = e - a1*(n2*n3);
  int a2 = r / n3;
  int a3 = r - a2*n3;
  double acc = 0.0;
  for (int i = 0; i < n1; ++i){
    for (int k = 0; k < n2; ++k){
      int m1 = i - l1, m2 = k - l2, m3 = m1 + m2;
      if (m3 < -l3 || m3 > l3) continue;
      double a = su2cg(l1, m1, l2, m2, l3, m3);
      if (a == 0.0) continue;
      cdbl q1 = Qval(l1, i, a1);
      cdbl q2 = Qval(l2, k, a2);
      cdbl q3 = Qval(l3, l3 + m3, a3);
      q3.im = -q3.im;                      // conj (Q3.conj().T)
      cdbl t = cmul(cmul(q1, q2), q3);
      acc += t.re * a;                     // imag cancels (asserted in ref)
    }
  }
  cg[C_OFF[p] + e] = (float)acc;
}

// ------------------------- fused main kernel -------------------------------

template<int P>
__device__ __forceinline__ void do_path(const float xall[9], const float x2v[9],
                                        const float* __restrict__ cg,  // uniform
                                        float* __restrict__ bbf,       // wave bounce
                                        float4* __restrict__ ob4, int t){
  constexpr int l1 = P_CH1[P], l2 = P_CH2[P];
  constexpr int n1 = 2*l1+1, n2 = 2*l2+1, no = 2*P_LO[P]+1;
  constexpr int XO  = (l1 == 0) ? 0 : (l1 == 1 ? 1 : 4);
  constexpr int X2O = X2_OFF[l2];
  constexpr int B4  = P_OUT[P] >> 2;   // float4 base of this chunk
  constexpr int NF4 = 16*no;           // float4 count in this chunk

  // lane-uniform M values, recomputed (same FMA order as the proven m_kernel)
  float m[no][n1];
  #pragma unroll
  for (int io = 0; io < no; ++io)
    #pragma unroll
    for (int i1 = 0; i1 < n1; ++i1){
      float s = 0.f;
      #pragma unroll
      for (int j = 0; j < n2; ++j)
        s = fmaf(cg[C_OFF[P] + (i1*n2 + j)*no + io], x2v[X2O + j], s);
      m[io][i1] = s;
    }

  // lane u's no outputs (same order as proven tp_bounce)
  #pragma unroll
  for (int io = 0; io < no; ++io){
    float acc = 0.f;
    #pragma unroll
    for (int i1 = 0; i1 < n1; ++i1)
      acc = fmaf(xall[XO + i1], m[io][i1], acc);
    bbf[t*no + io] = acc;              // odd stride -> <=2 lanes/bank, free
  }
  // compiler fence for cross-lane LDS (HW DS in-order per wave) — proven R7/R8
  __builtin_amdgcn_wave_barrier();
  asm volatile("" ::: "memory");

  const float4* bb4 = (const float4*)bbf;
  if constexpr (NF4 >= 64){
    ob4[B4 + t] = bb4[t];
    if constexpr (NF4 > 64){
      if (t < NF4 - 64) ob4[B4 + 64 + t] = bb4[64 + t];
    }
  } else {
    if (t < NF4) ob4[B4 + t] = bb4[t];
  }

  __builtin_amdgcn_wave_barrier();     // WAR: next path's writes stay after reads
  asm volatile("" ::: "memory");
}

// 256 threads = 4 waves = 4 rows, no __syncthreads (waves independent).
__global__ __launch_bounds__(256) void tp_fused(const float* __restrict__ x1,
    const float* __restrict__ x2, const float* __restrict__ cg,
    float* __restrict__ out, int batch){
  __shared__ __align__(16) float bnc[4][456];
  const int t = threadIdx.x & 63;
  int b = blockIdx.x * 4 + (threadIdx.x >> 6);
  if (b >= batch) b = batch - 1;            // benign duplicate
  b = __builtin_amdgcn_readfirstlane(b);
  float* bbf = bnc[threadIdx.x >> 6];

  // x1 channel values straight to registers
  const float* xr = x1 + (size_t)b * 576;
  float xall[9];
  xall[0] = xr[t];
  xall[1] = xr[64 + 3*t]; xall[2] = xr[65 + 3*t]; xall[3] = xr[66 + 3*t];
  #pragma unroll
  for (int i = 0; i < 5; ++i) xall[4+i] = xr[256 + 5*t + i];

  // x2 row: wave-uniform -> scalar loads
  const float* x2b = x2 + (size_t)b * 9;
  float x2v[9];
  #pragma unroll
  for (int j = 0; j < 9; ++j) x2v[j] = x2b[j];

  float4* ob4 = (float4*)(out + (size_t)b * 4608);

  do_path< 0>(xall, x2v, cg, bbf, ob4, t);
  do_path< 1>(xall, x2v, cg, bbf, ob4, t);
  do_path< 2>(xall, x2v, cg, bbf, ob4, t);
  do_path< 3>(xall, x2v, cg, bbf, ob4, t);
  do_path< 4>(xall, x2v, cg, bbf, ob4, t);
  do_path< 5>(xall, x2v, cg, bbf, ob4, t);
  do_path< 6>(xall, x2v, cg, bbf, ob4, t);
  do_path< 7>(xall, x2v, cg, bbf, ob4, t);
  do_path< 8>(xall, x2v, cg, bbf, ob4, t);
  do_path< 9>(xall, x2v, cg, bbf, ob4, t);
  do_path<10>(xall, x2v, cg, bbf, ob4, t);
  do_path<11>(xall, x2v, cg, bbf, ob4, t);
  do_path<12>(xall, x2v, cg, bbf, ob4, t);
  do_path<13>(xall, x2v, cg, bbf, ob4, t);
  do_path<14>(xall, x2v, cg, bbf, ob4, t);
  do_path<15>(xall, x2v, cg, bbf, ob4, t);
  do_path<16>(xall, x2v, cg, bbf, ob4, t);
  do_path<17>(xall, x2v, cg, bbf, ob4, t);
}

extern "C" void kernel_launch(void* const* d_in, const int* in_sizes, int n_in,
                              void* d_out, int out_size, void* d_ws, size_t ws_size,
                              hipStream_t stream){
  const float* x1 = (const float*)d_in[0];
  const float* x2 = (const float*)d_in[1];
  float* out = (float*)d_out;
  const int batch = in_sizes[0] / 576;

  float* cg = (float*)d_ws;                       // 1000 floats (ws >= 4 KiB)

  cg_init<<<NP, 256, 0, stream>>>(cg);
  tp_fused<<<(batch + 3)/4, 256, 0, stream>>>(x1, x2, cg, out, batch);
}

// Round 10
// 66.775 us; speedup vs baseline: 2.9129x; 1.4500x over previous
//
#include <hip/hip_runtime.h>

// ---------------------------------------------------------------------------
// e3nn tensor product: 64x0e+64x1o+64x2e  (x)  1x0e+1x1o+1x2e -> 18 CG paths,
// output sorted-concat to 72 floats per (batch, channel u), 4608 per batch row.
//
// R10: R9's proven fused structure + COMPILE-TIME CG tables (single change).
//  R8/R9 counters: VALUBusy 55%, per-pass 65us vs 45us store-ideal -> the
//  ~1000 runtime-cg FMAs/lane partially serialize with the store stream.
//  Constexpr CG (fp64, same algorithm as reference, Newton sqrt) makes the
//  coefficients immediates: ~65% fold away (zeros), rest are v_fmac literals.
//  cg_init + d_ws use deleted -> single dispatch.
//  De-risked vs R4: R4 bundled constexpr tables with an UNFENCED cross-lane
//  bounce; the fenced bounce is proven (R7/R8/R9, runtime cg). Only delta
//  tested this round is the constexpr values.
//
// Path p : (l1, l2, lo)
//  0:(0,0,0) 1:(0,1,1) 2:(0,2,2) 3:(1,0,1) 4:(1,1,0) 5:(1,1,1) 6:(1,1,2)
//  7:(1,2,1) 8:(1,2,2) 9:(1,2,3) 10:(2,0,2) 11:(2,1,1) 12:(2,1,2) 13:(2,1,3)
// 14:(2,2,0) 15:(2,2,1) 16:(2,2,2) 17:(2,2,3)
// Sorted output order: [0,4,14 | 1,3,7,11 | 5,15 | 2,6,10,16 | 8,12 | 9,13 | 17]
// ---------------------------------------------------------------------------

namespace {
constexpr int NP = 18;
constexpr int P_CH1[NP] = {0,0,0,1,1,1,1,1,1,1,2,2,2,2,2,2,2,2}; // l1
constexpr int P_CH2[NP] = {0,1,2,0,1,1,1,2,2,2,0,1,1,1,2,2,2,2}; // l2
constexpr int P_LO [NP] = {0,1,2,1,0,1,2,1,2,3,2,1,2,3,0,1,2,3};
constexpr int P_OUT[NP] = {0,192,1344,384,64,960,1664,576,2624,3264,
                           1984,768,2944,3712,128,1152,2304,4160};
constexpr int X2_OFF[3] = {0,1,4};

// ------------------ compile-time CG construction (fp64) -------------------

constexpr double cfact(int n){
  double r = 1.0;
  for (int i = 2; i <= n; ++i) r *= (double)i;
  return r;
}

constexpr double csqrt(double a){
  if (a <= 0.0) return 0.0;
  double s = 1.0;
  while (a > 1.0)  { a *= 0.25; s *= 2.0; }
  while (a < 0.25) { a *= 4.0;  s *= 0.5; }
  double x = 0.7;
  for (int i = 0; i < 12; ++i) x = 0.5*(x + a/x);  // quadratic conv., exact by ~5
  return x * s;
}

constexpr double su2cg_c(int j1,int m1,int j2,int m2,int j3,int m3){
  if (m1 + m2 != m3) return 0.0;
  int vmin = -j1 + j2 + m3; if (-j1 + m1 > vmin) vmin = -j1 + m1; if (0 > vmin) vmin = 0;
  int vmax = j2 + j3 + m1; if (j3 - j1 + j2 < vmax) vmax = j3 - j1 + j2; if (j3 + m3 < vmax) vmax = j3 + m3;
  if (vmax < vmin) return 0.0;
  double C = csqrt((2.0*j3 + 1.0)
      * cfact(j3 + j1 - j2) * cfact(j3 - j1 + j2) * cfact(j1 + j2 - j3)
      * cfact(j3 + m3) * cfact(j3 - m3)
      / (cfact(j1 + j2 + j3 + 1) * cfact(j1 - m1) * cfact(j1 + m1)
         * cfact(j2 - m2) * cfact(j2 + m2)));
  double S = 0.0;
  for (int v = vmin; v <= vmax; ++v){
    double t = cfact(j2 + j3 + m1 - v) * cfact(j1 - m1 + v)
        / (cfact(v) * cfact(j3 - j1 + j2 - v) * cfact(j3 + m3 - v)
           * cfact(v + j1 - j2 - m3));
    S += (((v + j2 + m2) & 1) ? -t : t);
  }
  return C * S;
}

struct CD { double re, im; };
constexpr CD cmulc(CD a, CD b){ return { a.re*b.re - a.im*b.im, a.re*b.im + a.im*b.re }; }

// change_basis_real_to_complex(l)[row][col] including the (-i)^l prefactor
constexpr CD qval(int l, int row, int col){
  const double s2 = 0.70710678118654752440;
  int m = row - l;
  CD v = {0.0, 0.0};
  if (m < 0){
    if (col == l - m)      v = { s2, 0.0 };
    else if (col == l + m) v = { 0.0, -s2 };
  } else if (m == 0){
    if (col == l)          v = { 1.0, 0.0 };
  } else {
    double sg = (m & 1) ? -1.0 : 1.0;
    if (col == l + m)      v = { sg*s2, 0.0 };
    else if (col == l - m) v = { 0.0, sg*s2 };
  }
  CD ph = {1.0, 0.0};
  switch (l & 3){            // (-i)^l
    case 0: ph = { 1.0, 0.0 }; break;
    case 1: ph = { 0.0,-1.0 }; break;
    case 2: ph = {-1.0, 0.0 }; break;
    default: ph = { 0.0, 1.0 }; break;
  }
  return cmulc(ph, v);
}

template<int L1,int L2,int L3>
struct CGArr { float v[(2*L1+1)*(2*L2+1)*(2*L3+1)]; };

template<int L1,int L2,int L3>
constexpr CGArr<L1,L2,L3> make_cg(){
  constexpr int n1 = 2*L1+1, n2 = 2*L2+1, n3 = 2*L3+1;
  CGArr<L1,L2,L3> T{};
  double su[n1][n2]{};
  for (int i = 0; i < n1; ++i)
    for (int k = 0; k < n2; ++k){
      int m1 = i - L1, m2 = k - L2, m3 = m1 + m2;
      su[i][k] = (m3 < -L3 || m3 > L3) ? 0.0 : su2cg_c(L1,m1,L2,m2,L3,m3);
    }
  for (int a1 = 0; a1 < n1; ++a1)
    for (int a2 = 0; a2 < n2; ++a2)
      for (int a3 = 0; a3 < n3; ++a3){
        double acc = 0.0;
        for (int i = 0; i < n1; ++i)
          for (int k = 0; k < n2; ++k){
            if (su[i][k] == 0.0) continue;
            CD q1 = qval(L1, i, a1);
            CD q2 = qval(L2, k, a2);
            CD q3 = qval(L3, L3 + (i-L1) + (k-L2), a3);
            q3.im = -q3.im;                  // conj(Q3)^T
            acc += cmulc(cmulc(q1,q2),q3).re * su[i][k];
          }
        // snap cancellation residues to exact zero so the FMA folds away
        if (acc < 1e-12 && acc > -1e-12) acc = 0.0;
        T.v[(a1*n2 + a2)*n3 + a3] = (float)acc;
      }
  return T;
}

template<int P>
struct CGH {
  static constexpr auto T = make_cg<P_CH1[P], P_CH2[P], P_LO[P]>();
};
} // namespace

// ------------------------- fused main kernel -------------------------------

template<int P>
__device__ __forceinline__ void do_path(const float xall[9], const float x2v[9],
                                        float* __restrict__ bbf,       // wave bounce
                                        float4* __restrict__ ob4, int t){
  constexpr int l1 = P_CH1[P], l2 = P_CH2[P];
  constexpr int n1 = 2*l1+1, n2 = 2*l2+1, no = 2*P_LO[P]+1;
  constexpr int XO  = (l1 == 0) ? 0 : (l1 == 1 ? 1 : 4);
  constexpr int X2O = X2_OFF[l2];
  constexpr int B4  = P_OUT[P] >> 2;   // float4 base of this chunk
  constexpr int NF4 = 16*no;           // float4 count in this chunk

  // lane-uniform M values from IMMEDIATE CG coefficients; zeros folded out
  float m[no][n1];
  #pragma unroll
  for (int io = 0; io < no; ++io)
    #pragma unroll
    for (int i1 = 0; i1 < n1; ++i1){
      float s = 0.f;
      #pragma unroll
      for (int j = 0; j < n2; ++j){
        const float c = CGH<P>::T.v[(i1*n2 + j)*no + io];  // compile-time const
        if (c != 0.f) s = fmaf(c, x2v[X2O + j], s);        // folds when c==0
      }
      m[io][i1] = s;
    }

  // lane u's no outputs (same order as proven R7/R8/R9 chain)
  #pragma unroll
  for (int io = 0; io < no; ++io){
    float acc = 0.f;
    #pragma unroll
    for (int i1 = 0; i1 < n1; ++i1)
      acc = fmaf(xall[XO + i1], m[io][i1], acc);
    bbf[t*no + io] = acc;              // odd stride -> <=2 lanes/bank, free
  }
  // compiler fence for cross-lane LDS (HW DS in-order per wave) — proven R7-R9
  __builtin_amdgcn_wave_barrier();
  asm volatile("" ::: "memory");

  const float4* bb4 = (const float4*)bbf;
  if constexpr (NF4 >= 64){
    ob4[B4 + t] = bb4[t];
    if constexpr (NF4 > 64){
      if (t < NF4 - 64) ob4[B4 + 64 + t] = bb4[64 + t];
    }
  } else {
    if (t < NF4) ob4[B4 + t] = bb4[t];
  }

  __builtin_amdgcn_wave_barrier();     // WAR: next path's writes stay after reads
  asm volatile("" ::: "memory");
}

// 256 threads = 4 waves = 4 rows, no __syncthreads (waves independent).
__global__ __launch_bounds__(256) void tp_fused(const float* __restrict__ x1,
    const float* __restrict__ x2, float* __restrict__ out, int batch){
  __shared__ __align__(16) float bnc[4][456];
  const int t = threadIdx.x & 63;
  int b = blockIdx.x * 4 + (threadIdx.x >> 6);
  if (b >= batch) b = batch - 1;            // benign duplicate
  b = __builtin_amdgcn_readfirstlane(b);
  float* bbf = bnc[threadIdx.x >> 6];

  // x1 channel values straight to registers
  const float* xr = x1 + (size_t)b * 576;
  float xall[9];
  xall[0] = xr[t];
  xall[1] = xr[64 + 3*t]; xall[2] = xr[65 + 3*t]; xall[3] = xr[66 + 3*t];
  #pragma unroll
  for (int i = 0; i < 5; ++i) xall[4+i] = xr[256 + 5*t + i];

  // x2 row: wave-uniform -> scalar loads
  const float* x2b = x2 + (size_t)b * 9;
  float x2v[9];
  #pragma unroll
  for (int j = 0; j < 9; ++j) x2v[j] = x2b[j];

  float4* ob4 = (float4*)(out + (size_t)b * 4608);

  do_path< 0>(xall, x2v, bbf, ob4, t);
  do_path< 1>(xall, x2v, bbf, ob4, t);
  do_path< 2>(xall, x2v, bbf, ob4, t);
  do_path< 3>(xall, x2v, bbf, ob4, t);
  do_path< 4>(xall, x2v, bbf, ob4, t);
  do_path< 5>(xall, x2v, bbf, ob4, t);
  do_path< 6>(xall, x2v, bbf, ob4, t);
  do_path< 7>(xall, x2v, bbf, ob4, t);
  do_path< 8>(xall, x2v, bbf, ob4, t);
  do_path< 9>(xall, x2v, bbf, ob4, t);
  do_path<10>(xall, x2v, bbf, ob4, t);
  do_path<11>(xall, x2v, bbf, ob4, t);
  do_path<12>(xall, x2v, bbf, ob4, t);
  do_path<13>(xall, x2v, bbf, ob4, t);
  do_path<14>(xall, x2v, bbf, ob4, t);
  do_path<15>(xall, x2v, bbf, ob4, t);
  do_path<16>(xall, x2v, bbf, ob4, t);
  do_path<17>(xall, x2v, bbf, ob4, t);
}

extern "C" void kernel_launch(void* const* d_in, const int* in_sizes, int n_in,
                              void* d_out, int out_size, void* d_ws, size_t ws_size,
                              hipStream_t stream){
  const float* x1 = (const float*)d_in[0];
  const float* x2 = (const float*)d_in[1];
  float* out = (float*)d_out;
  const int batch = in_sizes[0] / 576;
  tp_fused<<<(batch + 3)/4, 256, 0, stream>>>(x1, x2, out, batch);
}

// Round 11
// 65.929 us; speedup vs baseline: 2.9503x; 1.0128x over previous
//
#include <hip/hip_runtime.h>

// ---------------------------------------------------------------------------
// e3nn tensor product: 64x0e+64x1o+64x2e  (x)  1x0e+1x1o+1x2e -> 18 CG paths,
// output sorted-concat to 72 floats per (batch, channel u), 4608 per batch row.
//
// R11: R10 (66.8us, ~5.3 TB/s effective, ~80% of composite roofline) + three
// cheap store-stream levers, values bit-identical:
//  1. path calls reordered to SORTED OUTPUT ORDER -> each wave's global-write
//     stream is strictly monotonic/sequential (the fill kernel's shape).
//  2. double-buffered LDS bounce with parity alternation -> WAR fence dropped
//     (>=1 fence of path p+1 separates read-buf(p) from write-buf(p+2));
//     path p+1 VALU now overlaps path p readback+store. 18 fences instead of 36.
//  3. no==1 paths (0,4,14) skip LDS entirely: lane t's acc IS out[base+t]
//     (identity permutation) -> direct dense dword stores.
// Constexpr CG tables (R10-proven): coefficients are immediates, zeros folded.
// Single dispatch, no d_ws.
//
// Path p : (l1, l2, lo)
//  0:(0,0,0) 1:(0,1,1) 2:(0,2,2) 3:(1,0,1) 4:(1,1,0) 5:(1,1,1) 6:(1,1,2)
//  7:(1,2,1) 8:(1,2,2) 9:(1,2,3) 10:(2,0,2) 11:(2,1,1) 12:(2,1,2) 13:(2,1,3)
// 14:(2,2,0) 15:(2,2,1) 16:(2,2,2) 17:(2,2,3)
// Sorted output order: [0,4,14 | 1,3,7,11 | 5,15 | 2,6,10,16 | 8,12 | 9,13 | 17]
// ---------------------------------------------------------------------------

namespace {
constexpr int NP = 18;
constexpr int P_CH1[NP] = {0,0,0,1,1,1,1,1,1,1,2,2,2,2,2,2,2,2}; // l1
constexpr int P_CH2[NP] = {0,1,2,0,1,1,1,2,2,2,0,1,1,1,2,2,2,2}; // l2
constexpr int P_LO [NP] = {0,1,2,1,0,1,2,1,2,3,2,1,2,3,0,1,2,3};
constexpr int P_OUT[NP] = {0,192,1344,384,64,960,1664,576,2624,3264,
                           1984,768,2944,3712,128,1152,2304,4160};
constexpr int X2_OFF[3] = {0,1,4};

// ------------------ compile-time CG construction (fp64) -------------------

constexpr double cfact(int n){
  double r = 1.0;
  for (int i = 2; i <= n; ++i) r *= (double)i;
  return r;
}

constexpr double csqrt(double a){
  if (a <= 0.0) return 0.0;
  double s = 1.0;
  while (a > 1.0)  { a *= 0.25; s *= 2.0; }
  while (a < 0.25) { a *= 4.0;  s *= 0.5; }
  double x = 0.7;
  for (int i = 0; i < 12; ++i) x = 0.5*(x + a/x);
  return x * s;
}

constexpr double su2cg_c(int j1,int m1,int j2,int m2,int j3,int m3){
  if (m1 + m2 != m3) return 0.0;
  int vmin = -j1 + j2 + m3; if (-j1 + m1 > vmin) vmin = -j1 + m1; if (0 > vmin) vmin = 0;
  int vmax = j2 + j3 + m1; if (j3 - j1 + j2 < vmax) vmax = j3 - j1 + j2; if (j3 + m3 < vmax) vmax = j3 + m3;
  if (vmax < vmin) return 0.0;
  double C = csqrt((2.0*j3 + 1.0)
      * cfact(j3 + j1 - j2) * cfact(j3 - j1 + j2) * cfact(j1 + j2 - j3)
      * cfact(j3 + m3) * cfact(j3 - m3)
      / (cfact(j1 + j2 + j3 + 1) * cfact(j1 - m1) * cfact(j1 + m1)
         * cfact(j2 - m2) * cfact(j2 + m2)));
  double S = 0.0;
  for (int v = vmin; v <= vmax; ++v){
    double t = cfact(j2 + j3 + m1 - v) * cfact(j1 - m1 + v)
        / (cfact(v) * cfact(j3 - j1 + j2 - v) * cfact(j3 + m3 - v)
           * cfact(v + j1 - j2 - m3));
    S += (((v + j2 + m2) & 1) ? -t : t);
  }
  return C * S;
}

struct CD { double re, im; };
constexpr CD cmulc(CD a, CD b){ return { a.re*b.re - a.im*b.im, a.re*b.im + a.im*b.re }; }

// change_basis_real_to_complex(l)[row][col] including the (-i)^l prefactor
constexpr CD qval(int l, int row, int col){
  const double s2 = 0.70710678118654752440;
  int m = row - l;
  CD v = {0.0, 0.0};
  if (m < 0){
    if (col == l - m)      v = { s2, 0.0 };
    else if (col == l + m) v = { 0.0, -s2 };
  } else if (m == 0){
    if (col == l)          v = { 1.0, 0.0 };
  } else {
    double sg = (m & 1) ? -1.0 : 1.0;
    if (col == l + m)      v = { sg*s2, 0.0 };
    else if (col == l - m) v = { 0.0, sg*s2 };
  }
  CD ph = {1.0, 0.0};
  switch (l & 3){            // (-i)^l
    case 0: ph = { 1.0, 0.0 }; break;
    case 1: ph = { 0.0,-1.0 }; break;
    case 2: ph = {-1.0, 0.0 }; break;
    default: ph = { 0.0, 1.0 }; break;
  }
  return cmulc(ph, v);
}

template<int L1,int L2,int L3>
struct CGArr { float v[(2*L1+1)*(2*L2+1)*(2*L3+1)]; };

template<int L1,int L2,int L3>
constexpr CGArr<L1,L2,L3> make_cg(){
  constexpr int n1 = 2*L1+1, n2 = 2*L2+1, n3 = 2*L3+1;
  CGArr<L1,L2,L3> T{};
  double su[n1][n2]{};
  for (int i = 0; i < n1; ++i)
    for (int k = 0; k < n2; ++k){
      int m1 = i - L1, m2 = k - L2, m3 = m1 + m2;
      su[i][k] = (m3 < -L3 || m3 > L3) ? 0.0 : su2cg_c(L1,m1,L2,m2,L3,m3);
    }
  for (int a1 = 0; a1 < n1; ++a1)
    for (int a2 = 0; a2 < n2; ++a2)
      for (int a3 = 0; a3 < n3; ++a3){
        double acc = 0.0;
        for (int i = 0; i < n1; ++i)
          for (int k = 0; k < n2; ++k){
            if (su[i][k] == 0.0) continue;
            CD q1 = qval(L1, i, a1);
            CD q2 = qval(L2, k, a2);
            CD q3 = qval(L3, L3 + (i-L1) + (k-L2), a3);
            q3.im = -q3.im;                  // conj(Q3)^T
            acc += cmulc(cmulc(q1,q2),q3).re * su[i][k];
          }
        if (acc < 1e-12 && acc > -1e-12) acc = 0.0;  // snap residue -> folds
        T.v[(a1*n2 + a2)*n3 + a3] = (float)acc;
      }
  return T;
}

template<int P>
struct CGH {
  static constexpr auto T = make_cg<P_CH1[P], P_CH2[P], P_LO[P]>();
};
} // namespace

// ------------------------- fused main kernel -------------------------------

template<int P>
__device__ __forceinline__ void do_path(const float xall[9], const float x2v[9],
                                        float* __restrict__ bbf,   // this path's buffer
                                        float* __restrict__ ob,
                                        float4* __restrict__ ob4, int t){
  constexpr int l1 = P_CH1[P], l2 = P_CH2[P];
  constexpr int n1 = 2*l1+1, n2 = 2*l2+1, no = 2*P_LO[P]+1;
  constexpr int XO  = (l1 == 0) ? 0 : (l1 == 1 ? 1 : 4);
  constexpr int X2O = X2_OFF[l2];
  constexpr int B4  = P_OUT[P] >> 2;   // float4 base of this chunk
  constexpr int NF4 = 16*no;           // float4 count in this chunk

  // lane-uniform M from immediate CG coefficients (zeros folded at compile time)
  float m[no][n1];
  #pragma unroll
  for (int io = 0; io < no; ++io)
    #pragma unroll
    for (int i1 = 0; i1 < n1; ++i1){
      float s = 0.f;
      #pragma unroll
      for (int j = 0; j < n2; ++j){
        const float c = CGH<P>::T.v[(i1*n2 + j)*no + io];
        if (c != 0.f) s = fmaf(c, x2v[X2O + j], s);
      }
      m[io][i1] = s;
    }

  // lane u's no outputs (FMA order identical to R10)
  float acc[no];
  #pragma unroll
  for (int io = 0; io < no; ++io){
    float a = 0.f;
    #pragma unroll
    for (int i1 = 0; i1 < n1; ++i1)
      a = fmaf(xall[XO + i1], m[io][i1], a);
    acc[io] = a;
  }

  if constexpr (no == 1){
    // identity permutation: lane t's value IS out[base+t]; skip LDS
    ob[P_OUT[P] + t] = acc[0];           // dense 256B wave-store
  } else {
    #pragma unroll
    for (int io = 0; io < no; ++io)
      bbf[t*no + io] = acc[io];          // odd stride -> conflict-free
    // RAW fence: cross-lane LDS (HW DS in-order per wave; proven R7-R10).
    // No trailing WAR fence: buffer parity alternates per bounce path, and
    // the NEXT path's fence separates read-buf(p) from write-buf(p+2).
    __builtin_amdgcn_wave_barrier();
    asm volatile("" ::: "memory");
    const float4* bb4 = (const float4*)bbf;
    if constexpr (NF4 >= 64){
      ob4[B4 + t] = bb4[t];
      if constexpr (NF4 > 64){
        if (t < NF4 - 64) ob4[B4 + 64 + t] = bb4[64 + t];
      }
    } else {
      if (t < NF4) ob4[B4 + t] = bb4[t];
    }
  }
}

// 256 threads = 4 waves = 4 rows, no __syncthreads (waves independent).
// Per-wave LDS: 2 x 448-float bounce buffers (double-buffered by call parity).
__global__ __launch_bounds__(256) void tp_fused(const float* __restrict__ x1,
    const float* __restrict__ x2, float* __restrict__ out, int batch){
  __shared__ __align__(16) float bnc[4][2][448];
  const int t = threadIdx.x & 63;
  int b = blockIdx.x * 4 + (threadIdx.x >> 6);
  if (b >= batch) b = batch - 1;            // benign duplicate
  b = __builtin_amdgcn_readfirstlane(b);
  float* bufA = bnc[threadIdx.x >> 6][0];
  float* bufB = bnc[threadIdx.x >> 6][1];

  // x1 channel values straight to registers
  const float* xr = x1 + (size_t)b * 576;
  float xall[9];
  xall[0] = xr[t];
  xall[1] = xr[64 + 3*t]; xall[2] = xr[65 + 3*t]; xall[3] = xr[66 + 3*t];
  #pragma unroll
  for (int i = 0; i < 5; ++i) xall[4+i] = xr[256 + 5*t + i];

  // x2 row: wave-uniform -> scalar loads
  const float* x2b = x2 + (size_t)b * 9;
  float x2v[9];
  #pragma unroll
  for (int j = 0; j < 9; ++j) x2v[j] = x2b[j];

  float* ob   = out + (size_t)b * 4608;
  float4* ob4 = (float4*)ob;

  // SORTED OUTPUT ORDER -> monotonic sequential write stream per wave.
  // Bounce paths alternate bufA/bufB (parity -> WAR-safe by fence counting).
  do_path< 0>(xall, x2v, bufA, ob, ob4, t);   // base    0, no=1 (direct)
  do_path< 4>(xall, x2v, bufA, ob, ob4, t);   // base   64, no=1 (direct)
  do_path<14>(xall, x2v, bufA, ob, ob4, t);   // base  128, no=1 (direct)
  do_path< 1>(xall, x2v, bufA, ob, ob4, t);   // base  192, no=3
  do_path< 3>(xall, x2v, bufB, ob, ob4, t);   // base  384, no=3
  do_path< 7>(xall, x2v, bufA, ob, ob4, t);   // base  576, no=3
  do_path<11>(xall, x2v, bufB, ob, ob4, t);   // base  768, no=3
  do_path< 5>(xall, x2v, bufA, ob, ob4, t);   // base  960, no=3
  do_path<15>(xall, x2v, bufB, ob, ob4, t);   // base 1152, no=3
  do_path< 2>(xall, x2v, bufA, ob, ob4, t);   // base 1344, no=5
  do_path< 6>(xall, x2v, bufB, ob, ob4, t);   // base 1664, no=5
  do_path<10>(xall, x2v, bufA, ob, ob4, t);   // base 1984, no=5
  do_path<16>(xall, x2v, bufB, ob, ob4, t);   // base 2304, no=5
  do_path< 8>(xall, x2v, bufA, ob, ob4, t);   // base 2624, no=5
  do_path<12>(xall, x2v, bufB, ob, ob4, t);   // base 2944, no=5
  do_path< 9>(xall, x2v, bufA, ob, ob4, t);   // base 3264, no=7
  do_path<13>(xall, x2v, bufB, ob, ob4, t);   // base 3712, no=7
  do_path<17>(xall, x2v, bufA, ob, ob4, t);   // base 4160, no=7
}

extern "C" void kernel_launch(void* const* d_in, const int* in_sizes, int n_in,
                              void* d_out, int out_size, void* d_ws, size_t ws_size,
                              hipStream_t stream){
  const float* x1 = (const float*)d_in[0];
  const float* x2 = (const float*)d_in[1];
  float* out = (float*)d_out;
  const int batch = in_sizes[0] / 576;
  tp_fused<<<(batch + 3)/4, 256, 0, stream>>>(x1, x2, out, batch);
}